// Round 4
// baseline (348.599 us; speedup 1.0000x reference)
//
#include <hip/hip_runtime.h>

// 2D Haar DWT, single fused pass, fully-coalesced loads AND stores.
// x: (BC, 1024, 1024) fp32 -> out: [LL | LH | HL | HH], each (BC, 512, 512) fp32.
// Per output pixel (i,j):
//   a=x[2i-1,2j-1] b=x[2i-1,2j] c=x[2i,2j-1] d=x[2i,2j]   (index -1 => 0)
//   LL=0.5(a+b+c+d) LH=0.5(c+d-a-b) HL=0.5((b-a)+(d-c)) HH=0.5((d-c)-(b-a))
//
// Thread layout: thread handles 2 output cols (one col-PAIR) x 2 output rows.
//   - loads: one float4 per input row (rows 4i2-1..4i2+2) at col 4*jp:
//     16-B lane stride => perfectly coalesced 1KB/wave per instruction.
//   - halo col 4jp-1 comes from the previous lane's .w via __shfl_up
//     (zero redundant global reads; lane 0 of each wave patches via L1 hit).
//   - stores: float2 per subband-row: 8-B lane stride, every 64-B sector
//     fully covered per instruction => NT stores stream at full rate.

typedef float fx4 __attribute__((ext_vector_type(4)));
typedef float fx2 __attribute__((ext_vector_type(2)));

__device__ __forceinline__ void haar_row(float hT, fx4 vT, float hB, fx4 vB,
                                         fx2& ll, fx2& lh, fx2& hl, fx2& hh)
{
    // out col j0 = 2jp:   a=hT,   b=vT.x, c=hB,   d=vB.x
    // out col j1 = 2jp+1: a=vT.y, b=vT.z, c=vB.y, d=vB.z
    float a0 = hT,   b0 = vT.x, c0 = hB,   d0 = vB.x;
    float a1 = vT.y, b1 = vT.z, c1 = vB.y, d1 = vB.z;

    float st0 = a0 + b0, dt0 = b0 - a0, sb0 = c0 + d0, db0 = d0 - c0;
    float st1 = a1 + b1, dt1 = b1 - a1, sb1 = c1 + d1, db1 = d1 - c1;

    ll = fx2{0.5f * (st0 + sb0), 0.5f * (st1 + sb1)};
    lh = fx2{0.5f * (sb0 - st0), 0.5f * (sb1 - st1)};
    hl = fx2{0.5f * (dt0 + db0), 0.5f * (dt1 + db1)};
    hh = fx2{0.5f * (db0 - dt0), 0.5f * (db1 - dt1)};
}

__global__ __launch_bounds__(256) void dwt_haar_kernel(
    const float* __restrict__ x, float* __restrict__ out, int n_bc)
{
    constexpr int W  = 1024;   // input width
    constexpr int Ho = 512;    // output height
    constexpr int Wo = 512;    // output width

    const long long S = (long long)n_bc * Ho * Wo; // subband size (elements)

    int g   = blockIdx.x * 256 + threadIdx.x;
    int jp  = g & 255;             // col-pair index (256 per output row)
    int rem = g >> 8;
    int i2  = rem & 255;           // row-pair index: out rows 2*i2, 2*i2+1
    int bc  = rem >> 8;            // image plane

    const int c0 = jp << 2;        // input col 4*jp
    // input row 4*i2, at col c0
    const float* rB = x + ((long long)bc << 20) + (long long)(i2 << 2) * W + c0;

    // ---- fully-coalesced float4 loads (rows B=4i2, C=4i2+1, D=4i2+2) ----
    fx4 vB = *(const fx4*)(rB);
    fx4 vC = *(const fx4*)(rB + W);
    fx4 vD = *(const fx4*)(rB + 2 * W);
    fx4 vA = fx4{0.f, 0.f, 0.f, 0.f};
    const bool have_top = (i2 > 0);     // wave-uniform
    if (have_top) vA = *(const fx4*)(rB - W);   // row A = 4*i2-1

    // ---- halo col 4jp-1: previous lane's .w (one shfl per row) ----
    float hA = __shfl_up(vA.w, 1);
    float hB = __shfl_up(vB.w, 1);
    float hC = __shfl_up(vC.w, 1);
    float hD = __shfl_up(vD.w, 1);
    if ((threadIdx.x & 63) == 0) {      // lane 0: shuffle gave own value
        if (jp == 0) {                  // left zero-pad
            hA = hB = hC = hD = 0.f;
        } else {                        // L1-hit scalar patch loads
            hB = rB[-1];
            hC = rB[W - 1];
            hD = rB[2 * W - 1];
            hA = have_top ? rB[-W - 1] : 0.f;
        }
    }

    // ---- compute both output rows ----
    fx2 ll0, lh0, hl0, hh0, ll1, lh1, hl1, hh1;
    haar_row(hA, vA, hB, vB, ll0, lh0, hl0, hh0); // out row 2*i2   (top=A, bot=B)
    haar_row(hC, vC, hD, vD, ll1, lh1, hl1, hh1); // out row 2*i2+1 (top=C, bot=D)

    // ---- non-temporal float2 stores (fully-covered 64B sectors per wave) ----
    const long long obase0 = ((long long)bc * Ho + 2 * i2) * Wo + (jp << 1);
    const long long obase1 = obase0 + Wo;

    __builtin_nontemporal_store(ll0, (fx2*)(out +         obase0));
    __builtin_nontemporal_store(lh0, (fx2*)(out +     S + obase0));
    __builtin_nontemporal_store(hl0, (fx2*)(out + 2 * S + obase0));
    __builtin_nontemporal_store(hh0, (fx2*)(out + 3 * S + obase0));
    __builtin_nontemporal_store(ll1, (fx2*)(out +         obase1));
    __builtin_nontemporal_store(lh1, (fx2*)(out +     S + obase1));
    __builtin_nontemporal_store(hl1, (fx2*)(out + 2 * S + obase1));
    __builtin_nontemporal_store(hh1, (fx2*)(out + 3 * S + obase1));
}

extern "C" void kernel_launch(void* const* d_in, const int* in_sizes, int n_in,
                              void* d_out, int out_size, void* d_ws, size_t ws_size,
                              hipStream_t stream) {
    const float* x = (const float*)d_in[0];
    float* out = (float*)d_out;

    const int n_bc = in_sizes[0] / (1024 * 1024);              // B*C = 48
    // one thread per (plane, row-pair, col-pair): 48 * 256 * 256
    const long long total_threads = (long long)n_bc * 256 * 256;
    const int blocks = (int)(total_threads / 256);             // 12288

    dwt_haar_kernel<<<blocks, 256, 0, stream>>>(x, out, n_bc);
}